// Round 1
// baseline (196.001 us; speedup 1.0000x reference)
//
#include <hip/hip_runtime.h>

// Problem constants
#define BB 8
#define NN 4096
#define CC 128
#define RR 16
#define EE 65536
#define NNODES 32768
#define NEDGES 524288
#define KW    2176               // K of fused GEMM: 16 rel * 128 + 128 root
#define SCAP  16                 // per-(dst,rel) bucket capacity (Poisson(1): P(ovf)~1e-8)
#define NT    64                 // nodes per agg block
#define ALP   136                // A-tile LDS row stride (shorts): 272B, 16B-aligned

typedef unsigned short ushort_t;
typedef short bf16x8 __attribute__((ext_vector_type(8)));
typedef float f32x4 __attribute__((ext_vector_type(4)));

__device__ __forceinline__ unsigned short f2b(float f) {
    unsigned u = __builtin_bit_cast(unsigned, f);
    unsigned r = (u + 0x7fffu + ((u >> 16) & 1u)) >> 16;   // RNE
    return (unsigned short)r;
}
__device__ __forceinline__ float b2f(unsigned short s) {
    return __builtin_bit_cast(float, (unsigned)s << 16);
}
__device__ __forceinline__ float ldf(const void* p, int j, int isbf) {
    return isbf ? b2f(((const ushort_t*)p)[j]) : ((const float*)p)[j];
}
__device__ __forceinline__ int ldi(const int* p, int j, int is64) {
    return p[j << is64];
}

// wave-parallel float-dtype probe: fp32 mantissa noise shows huge bf16 "exponent"
__device__ __forceinline__ int probe_isbf(const ushort_t* xf) {
    int t = threadIdx.x & 63;
    int bad = 0;
    for (int j = t; j < 512; j += 64) {
        unsigned e = (xf[j] >> 7) & 0xffu;
        if (e >= 160u) bad = 1;
    }
    return __ballot(bad) == 0ull;
}

// ---------- prep_k ----------
// [0,2048): per-(dst,rel) edge bucketing (FIRST: atomic/scatter latency overlaps casts)
// [2048,4096): cast x -> Xb bf16
// [4096,5184): build WT2[c][k'] = B^T for fused GEMM (k' = r*128+k, root at 2048+k)
// 5184: flags (isbf for agg)
__global__ __launch_bounds__(256) void prep_k(const void* __restrict__ x,
                                              const void* __restrict__ relw,
                                              const void* __restrict__ rootw,
                                              const int* __restrict__ ei,
                                              const int* __restrict__ et,
                                              ushort_t* __restrict__ Xb,
                                              ushort_t* __restrict__ WT2,
                                              int* __restrict__ dcnt2,
                                              int* __restrict__ bucket2,
                                              int* __restrict__ flags) {
    int bx = blockIdx.x, t = threadIdx.x;
    if (bx < 2048) {                       // ---- edge path: one edge per thread ----
        int lane = t & 63;
        int pa = (lane < 16) ? ei[2 * lane + 1] : 0;
        int pb = (lane < 16) ? et[2 * lane + 1] : 0;
        int w64i = (__ballot(pa != 0) == 0ull);
        int w64t = (__ballot(pb != 0) == 0ull);
        int tid = bx * 256 + t;            // < NEDGES
        int b = tid >> 16, e = tid & 65535;
        int src = ldi(ei, (b * 2) * EE + e, w64i);
        int dst = ldi(ei, (b * 2 + 1) * EE + e, w64i);
        int r = ldi(et, tid, w64t);
        int key = (((b << 12) + dst) << 4) | r;       // (gdst)*16 + r
        int pos = atomicAdd(&dcnt2[key], 1);
        if (pos < SCAP) bucket2[key * SCAP + pos] = (b << 12) + src;
    } else if (bx < 4096) {                // ---- cast_x: uint4 group per thread ----
        int isbf = probe_isbf((const ushort_t*)x);
        int tid = (bx - 2048) * 256 + t;   // < 524288
        if (isbf) {
            ((uint4*)Xb)[tid] = ((const uint4*)x)[tid];
        } else {
            const float4* xf = (const float4*)x;
            float4 a = xf[2 * tid], b = xf[2 * tid + 1];
            ushort4 o0, o1;
            o0.x = f2b(a.x); o0.y = f2b(a.y); o0.z = f2b(a.z); o0.w = f2b(a.w);
            o1.x = f2b(b.x); o1.y = f2b(b.y); o1.z = f2b(b.z); o1.w = f2b(b.w);
            ((ushort4*)Xb)[2 * tid] = o0; ((ushort4*)Xb)[2 * tid + 1] = o1;
        }
    } else if (bx < 5184) {                // ---- WT2: B^T layout [128][2176] ----
        int isbf = probe_isbf((const ushort_t*)x);
        int tid = (bx - 4096) * 256 + t;   // < 278528
        if (tid < 262144) {
            int c = tid >> 11, kk = tid & 2047;
            int r = kk >> 7, k = kk & 127;
            WT2[c * KW + kk] = f2b(ldf(relw, (r << 14) + (k << 7) + c, isbf));
        } else {
            int t2 = tid - 262144;         // < 16384
            int c = t2 >> 7, k = t2 & 127;
            WT2[c * KW + 2048 + k] = f2b(ldf(rootw, (k << 7) + c, isbf));
        }
    } else {                               // ---- flags ----
        int isbf = probe_isbf((const ushort_t*)x);
        if (t == 0) flags[0] = isbf;
    }
}

// ---------- agg_k: aggregate-first fused mean + GEMM + score ----------
// Block = 64 consecutive nodes, 256 threads (4 waves). 17 passes (16 rel + root):
//   build A-tile [64][128] bf16 in LDS (fp32 mean of Xb rows gathered from L2),
//   MFMA-accumulate out[64][128] with B-frags streamed from L2-resident WT2.
// Epilogue: +bias, relu, *linw, row-reduce -> scores. Y never materialized.
__global__ __launch_bounds__(256) void agg_k(const ushort_t* __restrict__ Xb,
                                             const ushort_t* __restrict__ WT2,
                                             const int* __restrict__ dcnt2,
                                             const int* __restrict__ bucket2,
                                             const void* __restrict__ bias,
                                             const void* __restrict__ linw,
                                             const void* __restrict__ linb,
                                             void* __restrict__ out,
                                             const int* __restrict__ flags) {
    __shared__ ushort_t A[NT * ALP];       // 17408 B
    __shared__ int cnt[NT * 16];           // 4096 B
    __shared__ float red[NT][5];           // 1280 B (pad 5)
    int bx = blockIdx.x, t = threadIdx.x;
    int isbf = flags[0];
    int n0 = bx * NT;

    #pragma unroll
    for (int i = 0; i < 4; ++i) cnt[i * 256 + t] = dcnt2[n0 * 16 + i * 256 + t];

    int nsub = t >> 2, tsub = t & 3;       // node-in-tile, 32-col group
    int wave = t >> 6, lane = t & 63, lrow = lane & 15, lq = lane >> 4;
    f32x4 acc[4][2] = {};                  // 4 m-frags x 2 n-frags per wave

    for (int pass = 0; pass < 17; ++pass) {
        __syncthreads();                   // prev MFMA done reading A (covers cnt at pass 0)
        if (pass == 16) {                  // root pass: A = Xb rows (coalesced copy)
            const uint4* s4 = (const uint4*)(Xb + (size_t)(n0 + nsub) * 128 + tsub * 32);
            uint4* d4 = (uint4*)(&A[nsub * ALP + tsub * 32]);
            #pragma unroll
            for (int i = 0; i < 4; ++i) d4[i] = s4[i];
        } else {                           // mean pass for relation = pass
            int cfull = cnt[nsub * 16 + pass];
            int ce = cfull > SCAP ? SCAP : cfull;
            float s[32];
            #pragma unroll
            for (int j = 0; j < 32; ++j) s[j] = 0.f;
            const int* bk = bucket2 + ((size_t)(n0 + nsub) * 16 + pass) * SCAP;
            for (int e2 = 0; e2 < ce; ++e2) {
                int gs = bk[e2];
                const unsigned* xr = (const unsigned*)(Xb + (size_t)gs * 128 + tsub * 32);
                #pragma unroll
                for (int j = 0; j < 16; ++j) {
                    unsigned u = xr[j];
                    s[2 * j]     += __builtin_bit_cast(float, u << 16);
                    s[2 * j + 1] += __builtin_bit_cast(float, u & 0xffff0000u);
                }
            }
            float w = (cfull > 0) ? 1.0f / (float)cfull : 0.f;
            uint4* d4 = (uint4*)(&A[nsub * ALP + tsub * 32]);
            #pragma unroll
            for (int i = 0; i < 4; ++i) {
                uint4 v;
                unsigned q0 = (unsigned)f2b(s[i * 8 + 0] * w) | ((unsigned)f2b(s[i * 8 + 1] * w) << 16);
                unsigned q1 = (unsigned)f2b(s[i * 8 + 2] * w) | ((unsigned)f2b(s[i * 8 + 3] * w) << 16);
                unsigned q2 = (unsigned)f2b(s[i * 8 + 4] * w) | ((unsigned)f2b(s[i * 8 + 5] * w) << 16);
                unsigned q3 = (unsigned)f2b(s[i * 8 + 6] * w) | ((unsigned)f2b(s[i * 8 + 7] * w) << 16);
                v.x = q0; v.y = q1; v.z = q2; v.w = q3;
                d4[i] = v;
            }
        }
        __syncthreads();
        // MFMA: K=128 for this pass; B-frags direct from L2-resident WT2
        const ushort_t* bp0 = WT2 + (size_t)((wave * 2) * 16 + lrow) * KW + pass * 128;
        const ushort_t* bp1 = bp0 + (size_t)16 * KW;
        #pragma unroll
        for (int ks = 0; ks < 4; ++ks) {
            int k0 = ks * 32 + lq * 8;
            bf16x8 a[4], b0, b1;
            #pragma unroll
            for (int mi = 0; mi < 4; ++mi)
                a[mi] = *(const bf16x8*)(&A[(mi * 16 + lrow) * ALP + k0]);
            b0 = *(const bf16x8*)(bp0 + k0);
            b1 = *(const bf16x8*)(bp1 + k0);
            #pragma unroll
            for (int mi = 0; mi < 4; ++mi) {
                acc[mi][0] = __builtin_amdgcn_mfma_f32_16x16x32_bf16(a[mi], b0, acc[mi][0], 0, 0, 0);
                acc[mi][1] = __builtin_amdgcn_mfma_f32_16x16x32_bf16(a[mi], b1, acc[mi][1], 0, 0, 0);
            }
        }
    }
    // Epilogue: out[n][c] = relu(acc + bias[c]) * linw[c], reduce over c
    int c0 = (wave * 2) * 16 + lrow, c1 = c0 + 16;
    float bi0 = ldf(bias, c0, isbf), bi1 = ldf(bias, c1, isbf);
    float lw0 = ldf(linw, c0, isbf), lw1 = ldf(linw, c1, isbf);
    #pragma unroll
    for (int mi = 0; mi < 4; ++mi)
        #pragma unroll
        for (int rg = 0; rg < 4; ++rg) {
            float p = fmaxf(acc[mi][0][rg] + bi0, 0.f) * lw0
                    + fmaxf(acc[mi][1][rg] + bi1, 0.f) * lw1;
            p += __shfl_xor(p, 1, 64);
            p += __shfl_xor(p, 2, 64);
            p += __shfl_xor(p, 4, 64);
            p += __shfl_xor(p, 8, 64);
            if (lrow == 0) red[mi * 16 + lq * 4 + rg][wave] = p;
        }
    __syncthreads();
    if (t < NT) {
        float res = red[t][0] + red[t][1] + red[t][2] + red[t][3] + ldf(linb, 0, isbf);
        if (isbf) ((ushort_t*)out)[n0 + t] = f2b(res);
        else      ((float*)out)[n0 + t] = res;
    }
}

extern "C" void kernel_launch(void* const* d_in, const int* in_sizes, int n_in,
                              void* d_out, int out_size, void* d_ws, size_t ws_size,
                              hipStream_t stream) {
    const void* x     = d_in[0];
    const int*  ei    = (const int*)d_in[1];
    const int*  et    = (const int*)d_in[2];
    const void* relw  = d_in[3];
    const void* rootw = d_in[4];
    const void* bias  = d_in[5];
    const void* linw  = d_in[6];
    const void* linb  = d_in[7];

    const size_t WS_NEED = 44597504;
    if (ws_size < WS_NEED) return;

    char* ws = (char*)d_ws;
    ushort_t* Xb      = (ushort_t*)(ws);                      //  8,388,608
    ushort_t* WT2     = (ushort_t*)(ws + 8388608);            //    557,056
    int*      dcnt2   = (int*)(ws + 8945664);                 //  2,097,152
    int*      bucket2 = (int*)(ws + 11042816);                // 33,554,432
    int*      flags   = (int*)(ws + 44597248);                //        256

    hipMemsetAsync(dcnt2, 0, 2097152, stream);
    prep_k<<<5185, 256, 0, stream>>>(x, relw, rootw, ei, et, Xb, WT2, dcnt2, bucket2, flags);
    agg_k<<<512, 256, 0, stream>>>(Xb, WT2, dcnt2, bucket2, bias, linw, linb, d_out, flags);
}

// Round 2
// 188.235 us; speedup vs baseline: 1.0413x; 1.0413x over previous
//
#include <hip/hip_runtime.h>

// Problem constants
#define BB 8
#define NN 4096
#define CC 128
#define RR 16
#define EE 65536
#define NNODES 32768
#define NEDGES 524288
#define KW    2176               // K of fused GEMM: 16 rel * 128 + 128 root
#define BCAP  48                 // per-dst bucket capacity (Poisson16: P(ovf)~2e-6 over all nodes)
#define SCAP  16                 // per-(node,rel) LDS list capacity (Poisson1: P(ovf)~1e-14)
#define NT    32                 // nodes per agg block
#define ALP   136                // A-tile LDS row stride (shorts): 272B, 16B-aligned

typedef unsigned short ushort_t;
typedef short bf16x8 __attribute__((ext_vector_type(8)));
typedef float f32x4 __attribute__((ext_vector_type(4)));

__device__ __forceinline__ unsigned short f2b(float f) {
    unsigned u = __builtin_bit_cast(unsigned, f);
    unsigned r = (u + 0x7fffu + ((u >> 16) & 1u)) >> 16;   // RNE
    return (unsigned short)r;
}
__device__ __forceinline__ float b2f(unsigned short s) {
    return __builtin_bit_cast(float, (unsigned)s << 16);
}
__device__ __forceinline__ float ldf(const void* p, int j, int isbf) {
    return isbf ? b2f(((const ushort_t*)p)[j]) : ((const float*)p)[j];
}
__device__ __forceinline__ int ldi(const int* p, int j, int is64) {
    return p[j << is64];
}

// wave-parallel float-dtype probe: fp32 mantissa noise shows huge bf16 "exponent"
__device__ __forceinline__ int probe_isbf(const ushort_t* xf) {
    int t = threadIdx.x & 63;
    int bad = 0;
    for (int j = t; j < 512; j += 64) {
        unsigned e = (xf[j] >> 7) & 0xffu;
        if (e >= 160u) bad = 1;
    }
    return __ballot(bad) == 0ull;
}

// ---------- prep_k ----------
// [0,2048): per-dst edge bucketing (dense 128KB counters / 6.3MB buckets), batch=bx&7
// [2048,4096): cast x -> Xb bf16, batch=bx2&7 (XCD-affine with agg)
// [4096,5184): build WT2[c][k'] = B^T (k' = r*128+k, root at 2048+k)
// 5184: flags
__global__ __launch_bounds__(256) void prep_k(const void* __restrict__ x,
                                              const void* __restrict__ relw,
                                              const void* __restrict__ rootw,
                                              const int* __restrict__ ei,
                                              const int* __restrict__ et,
                                              ushort_t* __restrict__ Xb,
                                              ushort_t* __restrict__ WT2,
                                              int* __restrict__ dcnt,
                                              int* __restrict__ bucket,
                                              int* __restrict__ flags) {
    int bx = blockIdx.x, t = threadIdx.x;
    if (bx < 2048) {                       // ---- edge path: one edge per thread ----
        int lane = t & 63;
        int pa = (lane < 16) ? ei[2 * lane + 1] : 0;
        int pb = (lane < 16) ? et[2 * lane + 1] : 0;
        int w64i = (__ballot(pa != 0) == 0ull);
        int w64t = (__ballot(pb != 0) == 0ull);
        int b = bx & 7;                    // batch -> XCD affinity
        int e = (bx >> 3) * 256 + t;       // < EE
        int src = ldi(ei, (b * 2) * EE + e, w64i);
        int dst = ldi(ei, (b * 2 + 1) * EE + e, w64i);
        int r = ldi(et, (b << 16) + e, w64t);
        int gd = (b << 12) + dst;
        int pos = atomicAdd(&dcnt[gd], 1);
        if (pos < BCAP)
            bucket[gd * BCAP + pos] = (((b << 12) + src) << 4) | r;
    } else if (bx < 4096) {                // ---- cast_x: uint4 per thread, batch-affine ----
        int isbf = probe_isbf((const ushort_t*)x);
        int bx2 = bx - 2048;
        int tid = (bx2 & 7) * 65536 + (bx2 >> 3) * 256 + t;   // < 524288
        if (isbf) {
            ((uint4*)Xb)[tid] = ((const uint4*)x)[tid];
        } else {
            const float4* xf = (const float4*)x;
            float4 a = xf[2 * tid], b = xf[2 * tid + 1];
            ushort4 o0, o1;
            o0.x = f2b(a.x); o0.y = f2b(a.y); o0.z = f2b(a.z); o0.w = f2b(a.w);
            o1.x = f2b(b.x); o1.y = f2b(b.y); o1.z = f2b(b.z); o1.w = f2b(b.w);
            ((ushort4*)Xb)[2 * tid] = o0; ((ushort4*)Xb)[2 * tid + 1] = o1;
        }
    } else if (bx < 5184) {                // ---- WT2: B^T layout [128][2176] ----
        int isbf = probe_isbf((const ushort_t*)x);
        int tid = (bx - 4096) * 256 + t;   // < 278528
        if (tid < 262144) {
            int c = tid >> 11, kk = tid & 2047;
            int r = kk >> 7, k = kk & 127;
            WT2[c * KW + kk] = f2b(ldf(relw, (r << 14) + (k << 7) + c, isbf));
        } else {
            int t2 = tid - 262144;         // < 16384
            int c = t2 >> 7, k = t2 & 127;
            WT2[c * KW + 2048 + k] = f2b(ldf(rootw, (k << 7) + c, isbf));
        }
    } else {                               // ---- flags ----
        int isbf = probe_isbf((const ushort_t*)x);
        if (t == 0) flags[0] = isbf;
    }
}

// ---------- agg_k: aggregate-first fused mean + GEMM + score ----------
// Block = 32 nodes of one batch (batch = bx&7 for XCD L2 affinity), 256 threads.
// Phase A: LDS counting-sort of the node's dense bucket into per-(node,rel) lists.
// Phase B: 17 passes (16 rel + root): build A[32][128] bf16 (fp32 means gathered
// from the XCD-L2-resident 1MB Xb batch slice), MFMA-accumulate 32x128 with
// B-frags streamed from L2-resident WT2. Epilogue fuses bias+relu+linw+reduce.
__global__ __launch_bounds__(256) void agg_k(const ushort_t* __restrict__ Xb,
                                             const ushort_t* __restrict__ WT2,
                                             const int* __restrict__ dcnt,
                                             const int* __restrict__ bucket,
                                             const void* __restrict__ bias,
                                             const void* __restrict__ linw,
                                             const void* __restrict__ linb,
                                             void* __restrict__ out,
                                             const int* __restrict__ flags) {
    __shared__ int scnt[NT * 16];              // per-(node,rel) counts
    __shared__ ushort_t srt[NT * 16 * SCAP];   // sorted src lists (16KB)
    __shared__ ushort_t A[NT * ALP];           // A-tile (8.7KB)
    __shared__ float red[NT][5];
    int bx = blockIdx.x, t = threadIdx.x;
    int isbf = flags[0];
    int n0 = (bx & 7) * NN + (bx >> 3) * NT;

    scnt[t] = 0; scnt[256 + t] = 0;
    __syncthreads();

    int nsub = t >> 3, tsub = t & 7;           // node-in-tile, 16-col group
    int gn = n0 + nsub;
    int nc = dcnt[gn]; if (nc > BCAP) nc = BCAP;
    const int* bk = bucket + gn * BCAP;
    for (int j = tsub; j < nc; j += 8) {
        int v = bk[j];
        int pos = atomicAdd(&scnt[(nsub << 4) + (v & 15)], 1);
        if (pos < SCAP)
            srt[(((nsub << 4) + (v & 15)) << 4) + pos] = (ushort_t)((unsigned)v >> 4);
    }

    int wave = t >> 6, lane = t & 63, lrow = lane & 15, lq = lane >> 4;
    int wn = wave << 5;                        // 32 output cols per wave
    f32x4 acc[2][2] = {};

    for (int pass = 0; pass < 17; ++pass) {
        __syncthreads();                       // prev MFMA done with A (covers sort at pass 0)
        if (pass == 16) {                      // root pass: A = Xb rows (coalesced copy)
            const uint4* s4 = (const uint4*)(Xb + (size_t)gn * 128 + tsub * 16);
            uint4* d4 = (uint4*)(&A[nsub * ALP + tsub * 16]);
            d4[0] = s4[0]; d4[1] = s4[1];
        } else {                               // mean pass for relation = pass
            int c = scnt[(nsub << 4) + pass];
            int ce = c > SCAP ? SCAP : c;
            float s[16];
            #pragma unroll
            for (int j = 0; j < 16; ++j) s[j] = 0.f;
            const ushort_t* lst = &srt[((nsub << 4) + pass) << 4];
            for (int e2 = 0; e2 < ce; ++e2) {
                int gs = lst[e2];              // LDS broadcast across the node's 8 threads
                const unsigned* xr = (const unsigned*)(Xb + (size_t)gs * 128 + tsub * 16);
                #pragma unroll
                for (int j = 0; j < 8; ++j) {
                    unsigned u = xr[j];
                    s[2 * j]     += __builtin_bit_cast(float, u << 16);
                    s[2 * j + 1] += __builtin_bit_cast(float, u & 0xffff0000u);
                }
            }
            float w = (c > 0) ? 1.0f / (float)c : 0.f;
            uint4 v0, v1;
            v0.x = (unsigned)f2b(s[0] * w)  | ((unsigned)f2b(s[1] * w) << 16);
            v0.y = (unsigned)f2b(s[2] * w)  | ((unsigned)f2b(s[3] * w) << 16);
            v0.z = (unsigned)f2b(s[4] * w)  | ((unsigned)f2b(s[5] * w) << 16);
            v0.w = (unsigned)f2b(s[6] * w)  | ((unsigned)f2b(s[7] * w) << 16);
            v1.x = (unsigned)f2b(s[8] * w)  | ((unsigned)f2b(s[9] * w) << 16);
            v1.y = (unsigned)f2b(s[10] * w) | ((unsigned)f2b(s[11] * w) << 16);
            v1.z = (unsigned)f2b(s[12] * w) | ((unsigned)f2b(s[13] * w) << 16);
            v1.w = (unsigned)f2b(s[14] * w) | ((unsigned)f2b(s[15] * w) << 16);
            uint4* d4 = (uint4*)(&A[nsub * ALP + tsub * 16]);
            d4[0] = v0; d4[1] = v1;
        }
        __syncthreads();
        // MFMA: K=128 for this pass; B-frags direct from L2-resident WT2
        const ushort_t* bp0 = WT2 + (size_t)(wn + lrow) * KW + pass * 128;
        const ushort_t* bp1 = WT2 + (size_t)(wn + 16 + lrow) * KW + pass * 128;
        #pragma unroll
        for (int ks = 0; ks < 4; ++ks) {
            int k0 = ks * 32 + lq * 8;
            bf16x8 a0 = *(const bf16x8*)(&A[lrow * ALP + k0]);
            bf16x8 a1 = *(const bf16x8*)(&A[(16 + lrow) * ALP + k0]);
            bf16x8 b0 = *(const bf16x8*)(bp0 + k0);
            bf16x8 b1 = *(const bf16x8*)(bp1 + k0);
            acc[0][0] = __builtin_amdgcn_mfma_f32_16x16x32_bf16(a0, b0, acc[0][0], 0, 0, 0);
            acc[0][1] = __builtin_amdgcn_mfma_f32_16x16x32_bf16(a0, b1, acc[0][1], 0, 0, 0);
            acc[1][0] = __builtin_amdgcn_mfma_f32_16x16x32_bf16(a1, b0, acc[1][0], 0, 0, 0);
            acc[1][1] = __builtin_amdgcn_mfma_f32_16x16x32_bf16(a1, b1, acc[1][1], 0, 0, 0);
        }
    }
    // Epilogue: out[n][c] = relu(acc + bias[c]) * linw[c], reduce over c
    int c0 = wn + lrow, c1 = wn + 16 + lrow;
    float bi0 = ldf(bias, c0, isbf), bi1 = ldf(bias, c1, isbf);
    float lw0 = ldf(linw, c0, isbf), lw1 = ldf(linw, c1, isbf);
    #pragma unroll
    for (int mi = 0; mi < 2; ++mi)
        #pragma unroll
        for (int rg = 0; rg < 4; ++rg) {
            float p = fmaxf(acc[mi][0][rg] + bi0, 0.f) * lw0
                    + fmaxf(acc[mi][1][rg] + bi1, 0.f) * lw1;
            p += __shfl_xor(p, 1, 64);
            p += __shfl_xor(p, 2, 64);
            p += __shfl_xor(p, 4, 64);
            p += __shfl_xor(p, 8, 64);
            if (lrow == 0) red[mi * 16 + lq * 4 + rg][wave] = p;
        }
    __syncthreads();
    if (t < NT) {
        float res = red[t][0] + red[t][1] + red[t][2] + red[t][3] + ldf(linb, 0, isbf);
        if (isbf) ((ushort_t*)out)[n0 + t] = f2b(res);
        else      ((float*)out)[n0 + t] = res;
    }
}

extern "C" void kernel_launch(void* const* d_in, const int* in_sizes, int n_in,
                              void* d_out, int out_size, void* d_ws, size_t ws_size,
                              hipStream_t stream) {
    const void* x     = d_in[0];
    const int*  ei    = (const int*)d_in[1];
    const int*  et    = (const int*)d_in[2];
    const void* relw  = d_in[3];
    const void* rootw = d_in[4];
    const void* bias  = d_in[5];
    const void* linw  = d_in[6];
    const void* linb  = d_in[7];

    const size_t WS_NEED = 15368448;
    if (ws_size < WS_NEED) return;

    char* ws = (char*)d_ws;
    ushort_t* Xb     = (ushort_t*)(ws);                       //  8,388,608
    ushort_t* WT2    = (ushort_t*)(ws + 8388608);             //    557,056
    int*      dcnt   = (int*)(ws + 8945664);                  //    131,072
    int*      bucket = (int*)(ws + 9076736);                  //  6,291,456 (32768*48*4)
    int*      flags  = (int*)(ws + 15368192);                 //        256

    hipMemsetAsync(dcnt, 0, 131072, stream);
    prep_k<<<5185, 256, 0, stream>>>(x, relw, rootw, ei, et, Xb, WT2, dcnt, bucket, flags);
    agg_k<<<1024, 256, 0, stream>>>(Xb, WT2, dcnt, bucket, bias, linw, linb, d_out, flags);
}

// Round 3
// 187.024 us; speedup vs baseline: 1.0480x; 1.0065x over previous
//
#include <hip/hip_runtime.h>

// Problem constants
#define BB 8
#define NN 4096
#define CC 128
#define RR 16
#define EE 65536
#define NNODES 32768
#define NEDGES 524288
#define KW    2176               // K of fused GEMM: 16 rel * 128 + 128 root
#define BCAP  48                 // per-dst bucket capacity (Poisson16: P(ovf)~2e-6 over all nodes)
#define SCAP  16                 // per-(node,rel) LDS list capacity (Poisson1: P(ovf)~1e-14)
#define NT    32                 // nodes per agg block
#define ALP   136                // A-tile LDS row stride (shorts): 272B, 16B-aligned

typedef unsigned short ushort_t;
typedef short bf16x8 __attribute__((ext_vector_type(8)));
typedef float f32x4 __attribute__((ext_vector_type(4)));

__device__ __forceinline__ unsigned short f2b(float f) {
    unsigned u = __builtin_bit_cast(unsigned, f);
    unsigned r = (u + 0x7fffu + ((u >> 16) & 1u)) >> 16;   // RNE
    return (unsigned short)r;
}
__device__ __forceinline__ float b2f(unsigned short s) {
    return __builtin_bit_cast(float, (unsigned)s << 16);
}
__device__ __forceinline__ float ldf(const void* p, int j, int isbf) {
    return isbf ? b2f(((const ushort_t*)p)[j]) : ((const float*)p)[j];
}
__device__ __forceinline__ int ldi(const int* p, int j, int is64) {
    return p[j << is64];
}

// wave-parallel float-dtype probe: fp32 mantissa noise shows huge bf16 "exponent"
__device__ __forceinline__ int probe_isbf(const ushort_t* xf) {
    int t = threadIdx.x & 63;
    int bad = 0;
    for (int j = t; j < 512; j += 64) {
        unsigned e = (xf[j] >> 7) & 0xffu;
        if (e >= 160u) bad = 1;
    }
    return __ballot(bad) == 0ull;
}

// ---------- flags_k: probe dtypes ONCE (all other kernels just load flags) ----------
__global__ __launch_bounds__(64) void flags_k(const void* __restrict__ x,
                                              const int* __restrict__ ei,
                                              const int* __restrict__ et,
                                              int* __restrict__ flags) {
    int t = threadIdx.x;
    int isbf = probe_isbf((const ushort_t*)x);
    int a = (t < 16) ? ei[2 * t + 1] : 0;
    int b = (t < 16) ? et[2 * t + 1] : 0;
    unsigned long long ma = __ballot(a != 0);
    unsigned long long mb = __ballot(b != 0);
    if (t == 0) {
        flags[0] = isbf;
        flags[1] = (ma == 0ull);
        flags[2] = (mb == 0ull);
    }
}

// ---------- prep_k ----------
// [0,512): edge bucketing, 4 edges/thread (pipelined atomics)
// [512,1024): cast x -> Xb bf16, 4 x uint4/thread
// [1024,1092): WT2 transpose via coalesced LDS tile (1 chunk of 32 k-rows per block)
__global__ __launch_bounds__(256) void prep_k(const void* __restrict__ x,
                                              const void* __restrict__ relw,
                                              const void* __restrict__ rootw,
                                              const int* __restrict__ ei,
                                              const int* __restrict__ et,
                                              ushort_t* __restrict__ Xb,
                                              ushort_t* __restrict__ WT2,
                                              int* __restrict__ dcnt,
                                              int* __restrict__ bucket,
                                              const int* __restrict__ flags) {
    int bx = blockIdx.x, t = threadIdx.x;
    if (bx < 512) {                        // ---- edge path ----
        int w64i = flags[1], w64t = flags[2];
        #pragma unroll
        for (int i = 0; i < 4; ++i) {
            int eidx = i * 131072 + bx * 256 + t;       // < NEDGES
            int b = eidx >> 16, e = eidx & 65535;
            int src = ldi(ei, (b * 2) * EE + e, w64i);
            int dst = ldi(ei, (b * 2 + 1) * EE + e, w64i);
            int r = ldi(et, eidx, w64t);
            int gd = (b << 12) + dst;
            int pos = atomicAdd(&dcnt[gd], 1);
            if (pos < BCAP)
                bucket[gd * BCAP + pos] = (((b << 12) + src) << 4) | r;
        }
    } else if (bx < 1024) {                // ---- cast_x ----
        int isbf = flags[0];
        int bx2 = bx - 512;
        #pragma unroll
        for (int i = 0; i < 4; ++i) {
            int tid = i * 131072 + bx2 * 256 + t;       // < 524288 uint4
            if (isbf) {
                ((uint4*)Xb)[tid] = ((const uint4*)x)[tid];
            } else {
                const float4* xf = (const float4*)x;
                float4 a = xf[2 * tid], b = xf[2 * tid + 1];
                ushort4 o0, o1;
                o0.x = f2b(a.x); o0.y = f2b(a.y); o0.z = f2b(a.z); o0.w = f2b(a.w);
                o1.x = f2b(b.x); o1.y = f2b(b.y); o1.z = f2b(b.z); o1.w = f2b(b.w);
                ((ushort4*)Xb)[2 * tid] = o0; ((ushort4*)Xb)[2 * tid + 1] = o1;
            }
        }
    } else {                               // ---- WT2 transpose, one 32-row chunk ----
        __shared__ ushort_t Ls[128 * 40];  // [c][k] tile, pad 40 (80B rows, 16B-aligned)
        int isbf = flags[0];
        int mb = bx - 1024;                // 0..67
        int mat = mb >> 2, chunk = mb & 3;
        const void* src = (mat == 16) ? rootw : relw;
        int base = (mat == 16) ? 2048 : mat * 128;
        int soff = (mat == 16) ? 0 : mat * 16384;
        int k0 = chunk * 32;
        #pragma unroll
        for (int i = 0; i < 16; ++i) {     // coalesced read: c fast
            int idx = t + i * 256;         // < 4096
            int k = idx >> 7, c = idx & 127;
            Ls[c * 40 + k] = f2b(ldf(src, soff + (k0 + k) * 128 + c, isbf));
        }
        __syncthreads();
        #pragma unroll
        for (int i = 0; i < 2; ++i) {      // 16B stores, contiguous per c
            int idx = t + i * 256;         // < 512
            int c = idx >> 2, k8 = idx & 3;
            uint4 v = *(const uint4*)(&Ls[c * 40 + k8 * 8]);
            *(uint4*)(WT2 + (size_t)c * KW + base + k0 + k8 * 8) = v;
        }
    }
}

// ---------- agg_k: aggregate-first, software-pipelined ----------
// Block = 32 nodes of one batch (bx&7 -> XCD L2 affinity), 256 threads.
// Sort: LDS counting-sort of dense bucket into per-(node,rel) lists.
// Pipeline: per pass p, ISSUE gather loads for pass p+1 (2 preloaded edges +
// dynamic tail), run MFMA cluster on A[p&1] under setprio, then finish/pack
// A[(p+1)&1]. ONE barrier per pass. Epilogue fuses bias+relu+linw+reduce.
__global__ __launch_bounds__(256) void agg_k(const ushort_t* __restrict__ Xb,
                                             const ushort_t* __restrict__ WT2,
                                             const int* __restrict__ dcnt,
                                             const int* __restrict__ bucket,
                                             const void* __restrict__ bias,
                                             const void* __restrict__ linw,
                                             const void* __restrict__ linb,
                                             void* __restrict__ out,
                                             const int* __restrict__ flags) {
    __shared__ int scnt[NT * 16];              // per-(node,rel) counts
    __shared__ ushort_t srt[NT * 16 * SCAP];   // sorted src lists (16KB)
    __shared__ ushort_t A[2][NT * ALP];        // double-buffered A-tile (17.4KB)
    __shared__ float red[NT][5];
    int bx = blockIdx.x, t = threadIdx.x;
    int isbf = flags[0];
    int n0 = (bx & 7) * NN + (bx >> 3) * NT;

    scnt[t] = 0; scnt[256 + t] = 0;
    __syncthreads();

    int nsub = t >> 3, tsub = t & 7;           // node-in-tile, 16-col group
    int gn = n0 + nsub;
    int nc = dcnt[gn]; if (nc > BCAP) nc = BCAP;
    const int* bk = bucket + gn * BCAP;
    for (int j = tsub; j < nc; j += 8) {
        int v = bk[j];
        int pos = atomicAdd(&scnt[(nsub << 4) + (v & 15)], 1);
        if (pos < SCAP)
            srt[(((nsub << 4) + (v & 15)) << 4) + pos] = (ushort_t)((unsigned)v >> 4);
    }
    __syncthreads();

    int wave = t >> 6, lane = t & 63, lrow = lane & 15, lq = lane >> 4;
    int wn = wave << 5;                        // 32 output cols per wave
    f32x4 acc[2][2] = {};

    // prologue: build A[0] for relation 0 (not overlapped; once)
    {
        int cf = scnt[nsub << 4];
        int ce = cf > SCAP ? SCAP : cf;
        const ushort_t* lst = &srt[(nsub << 4) << 4];
        float s[16];
        #pragma unroll
        for (int j = 0; j < 16; ++j) s[j] = 0.f;
        for (int e2 = 0; e2 < ce; ++e2) {
            int gs = lst[e2];
            const unsigned* xr = (const unsigned*)(Xb + (size_t)gs * 128 + tsub * 16);
            #pragma unroll
            for (int j = 0; j < 8; ++j) {
                unsigned u = xr[j];
                s[2 * j]     += __builtin_bit_cast(float, u << 16);
                s[2 * j + 1] += __builtin_bit_cast(float, u & 0xffff0000u);
            }
        }
        float w = (cf > 0) ? 1.0f / (float)cf : 0.f;
        uint4 v0, v1;
        v0.x = (unsigned)f2b(s[0] * w)  | ((unsigned)f2b(s[1] * w) << 16);
        v0.y = (unsigned)f2b(s[2] * w)  | ((unsigned)f2b(s[3] * w) << 16);
        v0.z = (unsigned)f2b(s[4] * w)  | ((unsigned)f2b(s[5] * w) << 16);
        v0.w = (unsigned)f2b(s[6] * w)  | ((unsigned)f2b(s[7] * w) << 16);
        v1.x = (unsigned)f2b(s[8] * w)  | ((unsigned)f2b(s[9] * w) << 16);
        v1.y = (unsigned)f2b(s[10] * w) | ((unsigned)f2b(s[11] * w) << 16);
        v1.z = (unsigned)f2b(s[12] * w) | ((unsigned)f2b(s[13] * w) << 16);
        v1.w = (unsigned)f2b(s[14] * w) | ((unsigned)f2b(s[15] * w) << 16);
        uint4* d4 = (uint4*)(&A[0][nsub * ALP + tsub * 16]);
        d4[0] = v0; d4[1] = v1;
    }
    __syncthreads();

    for (int p = 0; p < 17; ++p) {
        int np = p + 1;
        // ---- issue gather loads for pass np (hidden under MFMA) ----
        uint4 p0a, p0b, p1a, p1b;
        int cf = 0, ce = 0;
        const ushort_t* lst = nullptr;
        if (np < 16) {
            cf = scnt[(nsub << 4) + np];
            ce = cf > SCAP ? SCAP : cf;
            lst = &srt[((nsub << 4) + np) << 4];
            if (ce > 0) {
                const uint4* xr = (const uint4*)(Xb + (size_t)lst[0] * 128 + tsub * 16);
                p0a = xr[0]; p0b = xr[1];
            }
            if (ce > 1) {
                const uint4* xr = (const uint4*)(Xb + (size_t)lst[1] * 128 + tsub * 16);
                p1a = xr[0]; p1b = xr[1];
            }
        } else if (np == 16) {             // root pass: plain row copy
            const uint4* xr = (const uint4*)(Xb + (size_t)gn * 128 + tsub * 16);
            p0a = xr[0]; p0b = xr[1];
        }
        // ---- MFMA cluster on A[p&1]; B-frags from L2-resident WT2 ----
        const ushort_t* Ap = A[p & 1];
        const ushort_t* bp0 = WT2 + (size_t)(wn + lrow) * KW + p * 128;
        const ushort_t* bp1 = WT2 + (size_t)(wn + 16 + lrow) * KW + p * 128;
        __builtin_amdgcn_s_setprio(1);
        #pragma unroll
        for (int ks = 0; ks < 4; ++ks) {
            int k0 = ks * 32 + lq * 8;
            bf16x8 a0 = *(const bf16x8*)(&Ap[lrow * ALP + k0]);
            bf16x8 a1 = *(const bf16x8*)(&Ap[(16 + lrow) * ALP + k0]);
            bf16x8 b0 = *(const bf16x8*)(bp0 + k0);
            bf16x8 b1 = *(const bf16x8*)(bp1 + k0);
            acc[0][0] = __builtin_amdgcn_mfma_f32_16x16x32_bf16(a0, b0, acc[0][0], 0, 0, 0);
            acc[0][1] = __builtin_amdgcn_mfma_f32_16x16x32_bf16(a0, b1, acc[0][1], 0, 0, 0);
            acc[1][0] = __builtin_amdgcn_mfma_f32_16x16x32_bf16(a1, b0, acc[1][0], 0, 0, 0);
            acc[1][1] = __builtin_amdgcn_mfma_f32_16x16x32_bf16(a1, b1, acc[1][1], 0, 0, 0);
        }
        __builtin_amdgcn_s_setprio(0);
        // ---- finish gather, pack A[np&1] ----
        if (np < 16) {
            float s[16];
            #pragma unroll
            for (int j = 0; j < 16; ++j) s[j] = 0.f;
            if (ce > 0) {
                unsigned uu[8] = {p0a.x, p0a.y, p0a.z, p0a.w, p0b.x, p0b.y, p0b.z, p0b.w};
                #pragma unroll
                for (int j = 0; j < 8; ++j) {
                    s[2 * j]     += __builtin_bit_cast(float, uu[j] << 16);
                    s[2 * j + 1] += __builtin_bit_cast(float, uu[j] & 0xffff0000u);
                }
            }
            if (ce > 1) {
                unsigned uu[8] = {p1a.x, p1a.y, p1a.z, p1a.w, p1b.x, p1b.y, p1b.z, p1b.w};
                #pragma unroll
                for (int j = 0; j < 8; ++j) {
                    s[2 * j]     += __builtin_bit_cast(float, uu[j] << 16);
                    s[2 * j + 1] += __builtin_bit_cast(float, uu[j] & 0xffff0000u);
                }
            }
            for (int e2 = 2; e2 < ce; ++e2) {  // rare tail (P~8%)
                int gs = lst[e2];
                const unsigned* xr = (const unsigned*)(Xb + (size_t)gs * 128 + tsub * 16);
                #pragma unroll
                for (int j = 0; j < 8; ++j) {
                    unsigned u = xr[j];
                    s[2 * j]     += __builtin_bit_cast(float, u << 16);
                    s[2 * j + 1] += __builtin_bit_cast(float, u & 0xffff0000u);
                }
            }
            float w = (cf > 0) ? 1.0f / (float)cf : 0.f;
            uint4 v0, v1;
            v0.x = (unsigned)f2b(s[0] * w)  | ((unsigned)f2b(s[1] * w) << 16);
            v0.y = (unsigned)f2b(s[2] * w)  | ((unsigned)f2b(s[3] * w) << 16);
            v0.z = (unsigned)f2b(s[4] * w)  | ((unsigned)f2b(s[5] * w) << 16);
            v0.w = (unsigned)f2b(s[6] * w)  | ((unsigned)f2b(s[7] * w) << 16);
            v1.x = (unsigned)f2b(s[8] * w)  | ((unsigned)f2b(s[9] * w) << 16);
            v1.y = (unsigned)f2b(s[10] * w) | ((unsigned)f2b(s[11] * w) << 16);
            v1.z = (unsigned)f2b(s[12] * w) | ((unsigned)f2b(s[13] * w) << 16);
            v1.w = (unsigned)f2b(s[14] * w) | ((unsigned)f2b(s[15] * w) << 16);
            uint4* d4 = (uint4*)(&A[np & 1][nsub * ALP + tsub * 16]);
            d4[0] = v0; d4[1] = v1;
        } else if (np == 16) {
            uint4* d4 = (uint4*)(&A[np & 1][nsub * ALP + tsub * 16]);
            d4[0] = p0a; d4[1] = p0b;
        }
        if (p < 16) __syncthreads();
    }

    // Epilogue: out[n][c] = relu(acc + bias[c]) * linw[c], reduce over c
    int c0 = wn + lrow, c1 = wn + 16 + lrow;
    float bi0 = ldf(bias, c0, isbf), bi1 = ldf(bias, c1, isbf);
    float lw0 = ldf(linw, c0, isbf), lw1 = ldf(linw, c1, isbf);
    #pragma unroll
    for (int mi = 0; mi < 2; ++mi)
        #pragma unroll
        for (int rg = 0; rg < 4; ++rg) {
            float p = fmaxf(acc[mi][0][rg] + bi0, 0.f) * lw0
                    + fmaxf(acc[mi][1][rg] + bi1, 0.f) * lw1;
            p += __shfl_xor(p, 1, 64);
            p += __shfl_xor(p, 2, 64);
            p += __shfl_xor(p, 4, 64);
            p += __shfl_xor(p, 8, 64);
            if (lrow == 0) red[mi * 16 + lq * 4 + rg][wave] = p;
        }
    __syncthreads();
    if (t < NT) {
        float res = red[t][0] + red[t][1] + red[t][2] + red[t][3] + ldf(linb, 0, isbf);
        if (isbf) ((ushort_t*)out)[n0 + t] = f2b(res);
        else      ((float*)out)[n0 + t] = res;
    }
}

extern "C" void kernel_launch(void* const* d_in, const int* in_sizes, int n_in,
                              void* d_out, int out_size, void* d_ws, size_t ws_size,
                              hipStream_t stream) {
    const void* x     = d_in[0];
    const int*  ei    = (const int*)d_in[1];
    const int*  et    = (const int*)d_in[2];
    const void* relw  = d_in[3];
    const void* rootw = d_in[4];
    const void* bias  = d_in[5];
    const void* linw  = d_in[6];
    const void* linb  = d_in[7];

    const size_t WS_NEED = 15368448;
    if (ws_size < WS_NEED) return;

    char* ws = (char*)d_ws;
    ushort_t* Xb     = (ushort_t*)(ws);                       //  8,388,608
    ushort_t* WT2    = (ushort_t*)(ws + 8388608);             //    557,056
    int*      dcnt   = (int*)(ws + 8945664);                  //    131,072
    int*      bucket = (int*)(ws + 9076736);                  //  6,291,456 (32768*48*4)
    int*      flags  = (int*)(ws + 15368192);                 //        256

    hipMemsetAsync(dcnt, 0, 131072, stream);
    flags_k<<<1, 64, 0, stream>>>(x, ei, et, flags);
    prep_k<<<1092, 256, 0, stream>>>(x, relw, rootw, ei, et, Xb, WT2, dcnt, bucket, flags);
    agg_k<<<1024, 256, 0, stream>>>(Xb, WT2, dcnt, bucket, bias, linw, linb, d_out, flags);
}

// Round 4
// 144.383 us; speedup vs baseline: 1.3575x; 1.2953x over previous
//
#include <hip/hip_runtime.h>

// Problem constants
#define BB 8
#define NN 4096
#define CC 128
#define RR 16
#define EE 65536
#define NNODES 32768
#define NEDGES 524288
#define BCAP  48                 // per-dst bucket capacity (Poisson16: P(ovf)~2e-6 over all nodes)
#define SCAP  16                 // per-(node,rel) LDS list capacity (Poisson1: P(ovf)~1e-14)
#define NT    32                 // nodes per agg block
#define ALP   136                // A-tile LDS row stride (shorts): 272B, 16B-aligned, 2-way-bank-free

typedef unsigned short ushort_t;
typedef short bf16x8 __attribute__((ext_vector_type(8)));
typedef float f32x4 __attribute__((ext_vector_type(4)));

__device__ __forceinline__ unsigned short f2b(float f) {
    unsigned u = __builtin_bit_cast(unsigned, f);
    unsigned r = (u + 0x7fffu + ((u >> 16) & 1u)) >> 16;   // RNE
    return (unsigned short)r;
}
__device__ __forceinline__ float b2f(unsigned short s) {
    return __builtin_bit_cast(float, (unsigned)s << 16);
}
__device__ __forceinline__ float ldf(const void* p, int j, int isbf) {
    return isbf ? b2f(((const ushort_t*)p)[j]) : ((const float*)p)[j];
}
__device__ __forceinline__ int ldi(const int* p, int j, int is64) {
    return p[j << is64];
}
// v_cvt_pk_bf16_f32: D = {hi=bf16(s1), lo=bf16(s0)}, RNE — replaces 2 manual f2b + or
__device__ __forceinline__ unsigned cvtpk(float lo, float hi) {
    unsigned r;
    asm("v_cvt_pk_bf16_f32 %0, %1, %2" : "=v"(r) : "v"(lo), "v"(hi));
    return r;
}

// wave-parallel float-dtype probe: fp32 mantissa noise shows huge bf16 "exponent"
__device__ __forceinline__ int probe_isbf(const ushort_t* xf) {
    int t = threadIdx.x & 63;
    int bad = 0;
    for (int j = t; j < 512; j += 64) {
        unsigned e = (xf[j] >> 7) & 0xffu;
        if (e >= 160u) bad = 1;
    }
    return __ballot(bad) == 0ull;
}

#define GATHER_SUM(u, sb) do { \
    s[sb+0] += __builtin_bit_cast(float, (u).x << 16); \
    s[sb+1] += __builtin_bit_cast(float, (u).x & 0xffff0000u); \
    s[sb+2] += __builtin_bit_cast(float, (u).y << 16); \
    s[sb+3] += __builtin_bit_cast(float, (u).y & 0xffff0000u); \
    s[sb+4] += __builtin_bit_cast(float, (u).z << 16); \
    s[sb+5] += __builtin_bit_cast(float, (u).z & 0xffff0000u); \
    s[sb+6] += __builtin_bit_cast(float, (u).w << 16); \
    s[sb+7] += __builtin_bit_cast(float, (u).w & 0xffff0000u); \
} while (0)

// ---------- prep_k ----------
// [0,512): edge bucketing, 4 edges/thread, batch = bx&7 (XCD-affine with agg)
// [512,1024): cast x -> Xb bf16, 4 x uint4/thread, batch-affine
// [1024,1092): WT3 fragment-major swizzle: WT3[(pass*4+ks)*8+cg][lane][8] so each
//              MFMA B-frag is ONE contiguous 1KB wave-load (fixes 64-line scatter)
__global__ __launch_bounds__(256) void prep_k(const void* __restrict__ x,
                                              const void* __restrict__ relw,
                                              const void* __restrict__ rootw,
                                              const int* __restrict__ ei,
                                              const int* __restrict__ et,
                                              ushort_t* __restrict__ Xb,
                                              ushort_t* __restrict__ WT3,
                                              int* __restrict__ dcnt,
                                              int* __restrict__ bucket,
                                              int* __restrict__ flags) {
    int bx = blockIdx.x, t = threadIdx.x;
    if (bx < 512) {                        // ---- edge path ----
        int lane = t & 63;
        int pa = (lane < 16) ? ei[2 * lane + 1] : 0;
        int pb = (lane < 16) ? et[2 * lane + 1] : 0;
        int w64i = (__ballot(pa != 0) == 0ull);
        int w64t = (__ballot(pb != 0) == 0ull);
        int b = bx & 7;                    // batch -> XCD affinity
        #pragma unroll
        for (int i = 0; i < 4; ++i) {
            int e = (bx >> 3) * 1024 + i * 256 + t;     // < EE
            int src = ldi(ei, (b * 2) * EE + e, w64i);
            int dst = ldi(ei, (b * 2 + 1) * EE + e, w64i);
            int r = ldi(et, (b << 16) + e, w64t);
            int gd = (b << 12) + dst;
            int pos = atomicAdd(&dcnt[gd], 1);
            if (pos < BCAP)
                bucket[gd * BCAP + pos] = (((b << 12) + src) << 4) | r;
        }
    } else if (bx < 1024) {                // ---- cast_x, batch-affine ----
        int isbf = probe_isbf((const ushort_t*)x);
        int bx2 = bx - 512;
        int base = (bx2 & 7) * 65536 + (bx2 >> 3) * 256 + t;
        #pragma unroll
        for (int i = 0; i < 4; ++i) {
            int tid = base + i * 16384;                 // < 524288 uint4
            if (isbf) {
                ((uint4*)Xb)[tid] = ((const uint4*)x)[tid];
            } else {
                const float4* xf = (const float4*)x;
                float4 a = xf[2 * tid], b = xf[2 * tid + 1];
                ushort4 o0, o1;
                o0.x = f2b(a.x); o0.y = f2b(a.y); o0.z = f2b(a.z); o0.w = f2b(a.w);
                o1.x = f2b(b.x); o1.y = f2b(b.y); o1.z = f2b(b.z); o1.w = f2b(b.w);
                ((ushort4*)Xb)[2 * tid] = o0; ((ushort4*)Xb)[2 * tid + 1] = o1;
            }
        }
    } else {                               // ---- WT3 fragment-major build ----
        __shared__ ushort_t Ls[128 * 40];  // [c][k] tile of 32 k-rows, 16B-aligned rows
        int isbf = probe_isbf((const ushort_t*)x);
        int mb = bx - 1024;                // 0..67
        int mat = mb >> 2, chunk = mb & 3; // pass, 32-k chunk (=ks)
        const void* src = (mat == 16) ? rootw : relw;
        int soff = (mat == 16) ? 0 : mat * 16384;
        int k0 = chunk * 32;
        #pragma unroll
        for (int i = 0; i < 16; ++i) {     // coalesced read: c fast
            int idx = t + i * 256;         // < 4096
            int k = idx >> 7, c = idx & 127;
            Ls[c * 40 + k] = f2b(ldf(src, soff + (k0 + k) * 128 + c, isbf));
        }
        __syncthreads();
        #pragma unroll
        for (int i = 0; i < 2; ++i) {      // frag-major write: contiguous 1KB per frag
            int idx = t + i * 256;         // < 512 = 8 cg x 64 lanes
            int cg = idx >> 6, lane = idx & 63;
            int lrow = lane & 15, lq = lane >> 4;
            uint4 v = *(const uint4*)(&Ls[(cg * 16 + lrow) * 40 + lq * 8]);
            *(uint4*)(WT3 + ((size_t)((mat * 4 + chunk) * 8 + cg)) * 512 + lane * 8) = v;
        }
        if (mb == 0 && t == 0) flags[0] = isbf;
    }
}

// ---------- agg_k: aggregate-first, frag-major B, pipelined gather ----------
// Block = 32 nodes of one batch (bx&7 -> XCD L2 affinity), 256 threads.
// Sort once into per-(node,rel) lists; then 17 passes: stage next-pass gather
// (list via one ds_read_b128, <=4 edge-row loads in flight), MFMA pass p with
// contiguous 1KB B-frag loads from WT3, finish sums + cvt_pk pack, 1 barrier.
__global__ __launch_bounds__(256, 4) void agg_k(const ushort_t* __restrict__ Xb,
                                                const ushort_t* __restrict__ WT3,
                                                const int* __restrict__ dcnt,
                                                const int* __restrict__ bucket,
                                                const void* __restrict__ bias,
                                                const void* __restrict__ linw,
                                                const void* __restrict__ linb,
                                                void* __restrict__ out,
                                                const int* __restrict__ flags) {
    __shared__ int scnt[NT * 16];              // per-(node,rel) counts
    __shared__ ushort_t srt[NT * 16 * SCAP];   // sorted src lists (16KB)
    __shared__ ushort_t A[2][NT * ALP];        // double-buffered A-tile (17.4KB)
    __shared__ float red[NT][5];
    int bx = blockIdx.x, t = threadIdx.x;
    int isbf = flags[0];
    int n0 = (bx & 7) * NN + (bx >> 3) * NT;

    scnt[t] = 0; scnt[256 + t] = 0;
    __syncthreads();

    int nsub = t >> 3, tsub = t & 7;           // node-in-tile, 8 threads/node
    int gn = n0 + nsub;
    int offA = tsub * 8, offB = 64 + tsub * 8; // two contiguous 8-col octets
    int nc = dcnt[gn]; if (nc > BCAP) nc = BCAP;
    const int* bk = bucket + gn * BCAP;
    for (int j = tsub; j < nc; j += 8) {
        int v = bk[j];
        int pos = atomicAdd(&scnt[(nsub << 4) + (v & 15)], 1);
        if (pos < SCAP)
            srt[(((nsub << 4) + (v & 15)) << 4) + pos] = (ushort_t)((unsigned)v >> 4);
    }
    __syncthreads();

    int wave = t >> 6, lane = t & 63, lrow = lane & 15, lq = lane >> 4;
    f32x4 acc[2][2] = {};

    // prologue: build A[0] for relation 0 (serial, once)
    {
        int cf = scnt[nsub << 4];
        int ce = cf > SCAP ? SCAP : cf;
        const ushort_t* lst = &srt[nsub << 8];
        float s[16];
        #pragma unroll
        for (int j = 0; j < 16; ++j) s[j] = 0.f;
        for (int e = 0; e < ce; ++e) {
            const ushort_t* xr = Xb + (size_t)lst[e] * 128;
            uint4 ua = *(const uint4*)(xr + offA), ub = *(const uint4*)(xr + offB);
            GATHER_SUM(ua, 0); GATHER_SUM(ub, 8);
        }
        float w = (cf > 0) ? 1.0f / (float)cf : 0.f;
        uint4 va, vb;
        va.x = cvtpk(s[0] * w, s[1] * w);   va.y = cvtpk(s[2] * w, s[3] * w);
        va.z = cvtpk(s[4] * w, s[5] * w);   va.w = cvtpk(s[6] * w, s[7] * w);
        vb.x = cvtpk(s[8] * w, s[9] * w);   vb.y = cvtpk(s[10] * w, s[11] * w);
        vb.z = cvtpk(s[12] * w, s[13] * w); vb.w = cvtpk(s[14] * w, s[15] * w);
        *(uint4*)(&A[0][nsub * ALP + offA]) = va;
        *(uint4*)(&A[0][nsub * ALP + offB]) = vb;
    }
    __syncthreads();

    for (int p = 0; p < 17; ++p) {
        int np = p + 1;
        // ---- stage pass np: list in 1 ds_read_b128, <=4 edge-rows in flight ----
        uint4 r0a, r0b, r1a, r1b, r2a, r2b, r3a, r3b;
        int cf = 0, ce = 0;
        if (np < 16) {
            cf = scnt[(nsub << 4) + np];
            ce = cf > SCAP ? SCAP : cf;
            uint4 q0 = *(const uint4*)(&srt[((nsub << 4) + np) << 4]);
            int e0 = q0.x & 0xffffu, e1 = q0.x >> 16;
            int e2i = q0.y & 0xffffu, e3 = q0.y >> 16;
            if (ce > 0) { const ushort_t* xr = Xb + (size_t)e0 * 128;  r0a = *(const uint4*)(xr + offA); r0b = *(const uint4*)(xr + offB); }
            if (ce > 1) { const ushort_t* xr = Xb + (size_t)e1 * 128;  r1a = *(const uint4*)(xr + offA); r1b = *(const uint4*)(xr + offB); }
            if (ce > 2) { const ushort_t* xr = Xb + (size_t)e2i * 128; r2a = *(const uint4*)(xr + offA); r2b = *(const uint4*)(xr + offB); }
            if (ce > 3) { const ushort_t* xr = Xb + (size_t)e3 * 128;  r3a = *(const uint4*)(xr + offA); r3b = *(const uint4*)(xr + offB); }
        } else if (np == 16) {             // root pass: plain row copy
            const ushort_t* xr = Xb + (size_t)gn * 128;
            r0a = *(const uint4*)(xr + offA); r0b = *(const uint4*)(xr + offB);
        }
        // ---- MFMA on A[p&1]; B-frags = contiguous 1KB loads from WT3 ----
        const ushort_t* Ap = A[p & 1];
        const ushort_t* bw = WT3 + (size_t)p * 16384 + (wave * 2) * 512 + lane * 8;
        __builtin_amdgcn_s_setprio(1);
        #pragma unroll
        for (int ks = 0; ks < 4; ++ks) {
            int k0 = ks * 32 + lq * 8;
            bf16x8 a0 = *(const bf16x8*)(&Ap[lrow * ALP + k0]);
            bf16x8 a1 = *(const bf16x8*)(&Ap[(16 + lrow) * ALP + k0]);
            bf16x8 b0 = *(const bf16x8*)(bw + ks * 4096);
            bf16x8 b1 = *(const bf16x8*)(bw + ks * 4096 + 512);
            acc[0][0] = __builtin_amdgcn_mfma_f32_16x16x32_bf16(a0, b0, acc[0][0], 0, 0, 0);
            acc[0][1] = __builtin_amdgcn_mfma_f32_16x16x32_bf16(a0, b1, acc[0][1], 0, 0, 0);
            acc[1][0] = __builtin_amdgcn_mfma_f32_16x16x32_bf16(a1, b0, acc[1][0], 0, 0, 0);
            acc[1][1] = __builtin_amdgcn_mfma_f32_16x16x32_bf16(a1, b1, acc[1][1], 0, 0, 0);
        }
        __builtin_amdgcn_s_setprio(0);
        // ---- finish sums, pack A[np&1] ----
        if (np < 16) {
            float s[16];
            #pragma unroll
            for (int j = 0; j < 16; ++j) s[j] = 0.f;
            if (ce > 0) { GATHER_SUM(r0a, 0); GATHER_SUM(r0b, 8); }
            if (ce > 1) { GATHER_SUM(r1a, 0); GATHER_SUM(r1b, 8); }
            if (ce > 2) { GATHER_SUM(r2a, 0); GATHER_SUM(r2b, 8); }
            if (ce > 3) { GATHER_SUM(r3a, 0); GATHER_SUM(r3b, 8); }
            if (ce > 4) {                  // rare tail (P~0.4% per list)
                const ushort_t* lst = &srt[((nsub << 4) + np) << 4];
                for (int e4 = 4; e4 < ce; ++e4) {
                    const ushort_t* xr = Xb + (size_t)lst[e4] * 128;
                    uint4 ta = *(const uint4*)(xr + offA), tb = *(const uint4*)(xr + offB);
                    GATHER_SUM(ta, 0); GATHER_SUM(tb, 8);
                }
            }
            float w = (cf > 0) ? 1.0f / (float)cf : 0.f;
            uint4 va, vb;
            va.x = cvtpk(s[0] * w, s[1] * w);   va.y = cvtpk(s[2] * w, s[3] * w);
            va.z = cvtpk(s[4] * w, s[5] * w);   va.w = cvtpk(s[6] * w, s[7] * w);
            vb.x = cvtpk(s[8] * w, s[9] * w);   vb.y = cvtpk(s[10] * w, s[11] * w);
            vb.z = cvtpk(s[12] * w, s[13] * w); vb.w = cvtpk(s[14] * w, s[15] * w);
            *(uint4*)(&A[np & 1][nsub * ALP + offA]) = va;
            *(uint4*)(&A[np & 1][nsub * ALP + offB]) = vb;
        } else if (np == 16) {
            *(uint4*)(&A[np & 1][nsub * ALP + offA]) = r0a;
            *(uint4*)(&A[np & 1][nsub * ALP + offB]) = r0b;
        }
        if (p < 16) __syncthreads();
    }

    // Epilogue: out[n][c] = relu(acc + bias[c]) * linw[c], reduce over c
    int wn = wave << 5;
    int c0 = wn + lrow, c1 = wn + 16 + lrow;
    float bi0 = ldf(bias, c0, isbf), bi1 = ldf(bias, c1, isbf);
    float lw0 = ldf(linw, c0, isbf), lw1 = ldf(linw, c1, isbf);
    #pragma unroll
    for (int mi = 0; mi < 2; ++mi)
        #pragma unroll
        for (int rg = 0; rg < 4; ++rg) {
            float p = fmaxf(acc[mi][0][rg] + bi0, 0.f) * lw0
                    + fmaxf(acc[mi][1][rg] + bi1, 0.f) * lw1;
            p += __shfl_xor(p, 1, 64);
            p += __shfl_xor(p, 2, 64);
            p += __shfl_xor(p, 4, 64);
            p += __shfl_xor(p, 8, 64);
            if (lrow == 0) red[mi * 16 + lq * 4 + rg][wave] = p;
        }
    __syncthreads();
    if (t < NT) {
        float res = red[t][0] + red[t][1] + red[t][2] + red[t][3] + ldf(linb, 0, isbf);
        if (isbf) ((ushort_t*)out)[n0 + t] = f2b(res);
        else      ((float*)out)[n0 + t] = res;
    }
}

extern "C" void kernel_launch(void* const* d_in, const int* in_sizes, int n_in,
                              void* d_out, int out_size, void* d_ws, size_t ws_size,
                              hipStream_t stream) {
    const void* x     = d_in[0];
    const int*  ei    = (const int*)d_in[1];
    const int*  et    = (const int*)d_in[2];
    const void* relw  = d_in[3];
    const void* rootw = d_in[4];
    const void* bias  = d_in[5];
    const void* linw  = d_in[6];
    const void* linb  = d_in[7];

    const size_t WS_NEED = 15368448;
    if (ws_size < WS_NEED) return;

    char* ws = (char*)d_ws;
    ushort_t* Xb     = (ushort_t*)(ws);                       //  8,388,608
    ushort_t* WT3    = (ushort_t*)(ws + 8388608);             //    557,056
    int*      dcnt   = (int*)(ws + 8945664);                  //    131,072
    int*      bucket = (int*)(ws + 9076736);                  //  6,291,456 (32768*48*4)
    int*      flags  = (int*)(ws + 15368192);                 //        256

    hipMemsetAsync(dcnt, 0, 131072, stream);
    prep_k<<<1092, 256, 0, stream>>>(x, relw, rootw, ei, et, Xb, WT3, dcnt, bucket, flags);
    agg_k<<<1024, 256, 0, stream>>>(Xb, WT3, dcnt, bucket, bias, linw, linb, d_out, flags);
}